// Round 12
// baseline (400.244 us; speedup 1.0000x reference)
//
#include <hip/hip_runtime.h>
#include <stdint.h>

// WASLL R16: the fused-persistent-kernel experiment R14 MEANT to run.
// R15 post-mortem: gather path dead -- FETCH 490MB (64B-sector amplification
// of random 8B pos reads, straight from HBM at 3.2TB/s; L3 retains ~nothing).
// The 3-pass pipeline exists precisely to defeat that amplification (p2
// fetches 62.7MB). R14's fused kernel never ran: the NP%16384 guard
// (correctly) rejected NP=8M because the phase bodies had lost their
// partial-bucket handling. R16 ports R12's proven `valid`-guarded bodies
// verbatim into one 512-block x 512-thread persistent kernel:
//   A (p1) -> grid_bar -> B (p2, per dim) -> grid_bar -> C (p3, per dim)
//   - dual per-dim ent2 buffers: no barrier between C(d0) and B(d1)
//   - bench path (y only) = 2 barrier passages, 2 dispatches total (vs 6)
//   - residency: 76KB LDS -> exactly 2 blocks/CU x 256 CU = 512 = NBLK;
//     __launch_bounds__(512,4) caps VGPR at 128 (bodies proven 52-56)
//   - cursors+bar memset (partial buckets invalidate the rotation trick);
//     out zeroed by block 0 pre-barrier (release-fenced at bar 1)
// Falsifier: hang -> barrier/residency bug; total >= 265 -> boundary theory
// dead, R12 (269.7us) is the structural floor.

#define PINB_SHIFT 13
#define PINB_SIZE  (1 << PINB_SHIFT)      // 8192 pins/bucket = 32KB window
#define MAX_PINB   1024
#define JB_SHIFT   14
#define JB_SIZE    (1 << JB_SHIFT)        // 16384 slots/j-bucket (4096 nets)
#define MAX_JB     512
#define NTHR2      512                    // block size
#define NBLK       512                    // grid = 2 blocks/CU x 256 CU

__device__ __forceinline__ float wa4(float a, float b, float c, float d, float ig) {
    float ea = __expf(a * ig), eb = __expf(b * ig);
    float ec = __expf(c * ig), ed = __expf(d * ig);
    float na = __expf(-a * ig), nb = __expf(-b * ig);
    float nc = __expf(-c * ig), nd = __expf(-d * ig);
    float s_ep  = ea + eb + ec + ed;
    float s_xep = a * ea + b * eb + c * ec + d * ed;
    float s_en  = na + nb + nc + nd;
    float s_xen = a * na + b * nb + c * nc + d * nd;
    return s_xep / s_ep - s_xen / s_en;
}

// monotonic-ticket grid barrier; bar memset to 0 each launch. All NBLK
// blocks are co-resident by construction (LDS residency proof above).
__device__ __forceinline__ void grid_bar(unsigned* bar) {
    __syncthreads();                       // block's mem-ops all issued
    if (threadIdx.x == 0) {
        __threadfence();                   // release (device scope)
        unsigned tkt = atomicAdd(bar, 1u);
        unsigned tgt = (tkt / NBLK + 1u) * (unsigned)NBLK;
        while (atomicMax(bar, 0u) < tgt)   // coherent read-modify-nothing
            __builtin_amdgcn_s_sleep(8);
        __threadfence();                   // acquire
    }
    __syncthreads();
}

__global__ __launch_bounds__(NTHR2, 4) void fused_wasll(
    const int4* __restrict__ fnp4, const float2* __restrict__ pos2,
    const float* __restrict__ wts, const float* __restrict__ ig_p,
    const int* __restrict__ slrx_p, const int* __restrict__ slry_p,
    int NP, int n_pinb, int n_jb,
    uint2* __restrict__ ent1, uint2* __restrict__ ent2a,
    uint2* __restrict__ ent2b,
    unsigned* __restrict__ cur1, unsigned* __restrict__ cur2,
    unsigned* __restrict__ bar, float* __restrict__ out)
{
    __shared__ __align__(16) char smem[PINB_SIZE * sizeof(uint2) + 3 * MAX_PINB * 4]; // 76KB
    const int t = threadIdx.x;
    const bool dx = slrx_p[0] > 1, dy = slry_p[0] > 1;

    if (blockIdx.x == 0 && t == 0) out[0] = 0.0f;   // released at bar 1
    if (!dx && !dy) return;                // uniform decision: no barriers run

    // ---------------- phase A: partition (pin, j) by pin-bucket ----------------
    {
        uint2*    staged = (uint2*)smem;                                 // 64KB
        unsigned* hist   = (unsigned*)(smem + PINB_SIZE * sizeof(uint2));// 4KB
        unsigned* scn    = hist + MAX_PINB;                              // 4KB
        unsigned* gbase  = scn + MAX_PINB;                               // 4KB
        for (int c = blockIdx.x; c < n_pinb; c += NBLK) {                // <=2 chunks
            const int base  = c << PINB_SHIFT;
            const int valid = min(PINB_SIZE, NP - base);                 // mult of 4
            __syncthreads();               // prior-iter staged reads done
            for (int b = t; b < MAX_PINB; b += NTHR2) hist[b] = 0;
            __syncthreads();

            unsigned pin[16], rnk[16];
            #pragma unroll
            for (int m4 = 0; m4 < 4; ++m4) {
                int k4 = t + NTHR2 * m4;
                int kk = 4 * k4;
                int4 v = make_int4(0, 0, 0, 0);
                if (kk < valid) v = fnp4[(base >> 2) + k4];
                pin[4*m4+0] = (unsigned)v.x; pin[4*m4+1] = (unsigned)v.y;
                pin[4*m4+2] = (unsigned)v.z; pin[4*m4+3] = (unsigned)v.w;
            }
            #pragma unroll
            for (int m4 = 0; m4 < 4; ++m4)
                #pragma unroll
                for (int cc = 0; cc < 4; ++cc) {
                    int kk = 4 * (t + NTHR2 * m4) + cc;
                    rnk[4*m4+cc] = 0;
                    if (kk < valid)
                        rnk[4*m4+cc] = atomicAdd(&hist[pin[4*m4+cc] >> PINB_SHIFT], 1u);
                }
            __syncthreads();

            if (t < 64) {                  // wave-0 scan, 16 buckets/lane
                unsigned v[16], s = 0;
                #pragma unroll
                for (int i = 0; i < 16; ++i) { v[i] = hist[t * 16 + i]; s += v[i]; }
                unsigned e = s;
                #pragma unroll
                for (int off = 1; off < 64; off <<= 1) {
                    unsigned u = __shfl_up(e, off, 64);
                    if (t >= off) e += u;
                }
                e -= s;
                #pragma unroll
                for (int i = 0; i < 16; ++i) { scn[t * 16 + i] = e; e += v[i]; }
            }
            __syncthreads();

            // all-thread cursor atomics (zero-based cur1, bucket base added)
            for (int b = t; b < n_pinb; b += NTHR2)
                if (hist[b])
                    gbase[b] = ((unsigned)b << PINB_SHIFT) + atomicAdd(&cur1[b], hist[b]);
            __syncthreads();

            #pragma unroll
            for (int m4 = 0; m4 < 4; ++m4)
                #pragma unroll
                for (int cc = 0; cc < 4; ++cc) {
                    int kk = 4 * (t + NTHR2 * m4) + cc;
                    if (kk < valid) {
                        unsigned p = pin[4*m4+cc];
                        staged[scn[p >> PINB_SHIFT] + rnk[4*m4+cc]] =
                            make_uint2(p, (unsigned)(base + kk));
                    }
                }
            __syncthreads();

            for (int k = t; k < valid; k += NTHR2) {   // coalesced runs
                uint2 e = staged[k];
                unsigned b = e.x >> PINB_SHIFT;
                ent1[gbase[b] + ((unsigned)k - scn[b])] = e;
            }
        }
    }
    grid_bar(bar);

    // ---------------- per dim: phase B (gather+bin), phase C (eval) ----------------
    for (int d = 0; d < 2; ++d) {
        const bool act = d ? dy : dx;
        if (!act) continue;
        uint2*    ent2d = d ? ent2b : ent2a;   // disjoint: no C(d0)/B(d1) bar
        unsigned* cur2d = cur2 + d * MAX_JB;

        // phase B (R12 p2 body verbatim: 512t, 16-deep, win/staged alias)
        {
            float*    win    = (float*)smem;                                  // 32KB
            uint2*    staged = (uint2*)smem;                                  // 64KB
            unsigned* hist   = (unsigned*)(smem + PINB_SIZE * sizeof(uint2)); // 2KB
            unsigned* scn    = hist + MAX_JB;                                 // 2KB
            unsigned* gbase  = scn + MAX_JB;                                  // 2KB
            for (int b = blockIdx.x; b < n_pinb; b += NBLK) {                 // <=2 buckets
                const int pbase = b << PINB_SHIFT;
                const int valid = min(PINB_SIZE, NP - pbase);
                __syncthreads();           // prior-iter staged reads done

                uint2 e[16];
                #pragma unroll
                for (int m = 0; m < 16; ++m) {
                    int k = t + NTHR2 * m;
                    e[m] = make_uint2(0u, 0u);
                    if (k < valid) e[m] = ent1[pbase + k];
                }
                for (int i = t; i < valid; i += NTHR2) {      // coalesced window
                    float2 p = pos2[pbase + i];
                    win[i] = d ? p.y : p.x;
                }
                if (t < MAX_JB) hist[t] = 0;
                __syncthreads();

                float yv[16]; unsigned rnk[16];
                #pragma unroll
                for (int m = 0; m < 16; ++m) {
                    int k = t + NTHR2 * m;
                    yv[m] = (k < valid) ? win[e[m].x & (PINB_SIZE - 1)] : 0.0f;
                }
                #pragma unroll
                for (int m = 0; m < 16; ++m) {
                    int k = t + NTHR2 * m;
                    rnk[m] = 0;
                    if (k < valid) rnk[m] = atomicAdd(&hist[e[m].y >> JB_SHIFT], 1u);
                }
                __syncthreads();           // win reads + hist atomics done

                if (t < 64) {              // wave-0 scan, 8 buckets/lane
                    unsigned v[8], s = 0;
                    #pragma unroll
                    for (int i = 0; i < 8; ++i) { v[i] = hist[t * 8 + i]; s += v[i]; }
                    unsigned ex = s;
                    #pragma unroll
                    for (int off = 1; off < 64; off <<= 1) {
                        unsigned u = __shfl_up(ex, off, 64);
                        if (t >= off) ex += u;
                    }
                    ex -= s;
                    #pragma unroll
                    for (int i = 0; i < 8; ++i) { scn[t * 8 + i] = ex; ex += v[i]; }
                }
                __syncthreads();

                for (int q = t; q < n_jb; q += NTHR2)
                    if (hist[q])
                        gbase[q] = ((unsigned)q << JB_SHIFT) + atomicAdd(&cur2d[q], hist[q]);
                __syncthreads();

                #pragma unroll
                for (int m = 0; m < 16; ++m) {            // overwrites win
                    int k = t + NTHR2 * m;
                    if (k < valid)
                        staged[scn[e[m].y >> JB_SHIFT] + rnk[m]] =
                            make_uint2(e[m].y, __float_as_uint(yv[m]));
                }
                __syncthreads();

                for (int k = t; k < valid; k += NTHR2) {  // coalesced runs
                    uint2 s2 = staged[k];
                    unsigned jb = s2.x >> JB_SHIFT;
                    ent2d[gbase[jb] + ((unsigned)k - scn[jb])] = s2;
                }
            }
        }
        grid_bar(bar);

        // phase C (R12 p3 body, 512t)
        {
            float* ytmp = (float*)smem;                   // 64KB
            const float ig = ig_p[0];
            for (int jb = blockIdx.x; jb < n_jb; jb += NBLK) {  // <=1 bucket
                const int base_j = jb << JB_SHIFT;
                const int nslots = min(JB_SIZE, NP - base_j);   // mult of 4
                __syncthreads();
                for (int k = t; k < nslots; k += NTHR2) { // coalesced read
                    uint2 e = ent2d[base_j + k];
                    ytmp[e.x & (JB_SIZE - 1)] = __uint_as_float(e.y);
                }
                __syncthreads();

                float val = 0.0f;
                const int nnets = nslots >> 2, bnet = base_j >> 2;
                const float4* y4 = (const float4*)ytmp;
                for (int i = t; i < nnets; i += NTHR2) {
                    float4 p = y4[i];                     // ds_read_b128
                    val += wts[bnet + i] * wa4(p.x, p.y, p.z, p.w, ig);
                }
                #pragma unroll
                for (int off = 32; off > 0; off >>= 1)
                    val += __shfl_down(val, off, 64);
                __syncthreads();           // y4 reads done before scratch write
                if ((t & 63) == 0) ytmp[t >> 6] = val;
                __syncthreads();
                if (t == 0) {
                    float s = 0.0f;
                    #pragma unroll
                    for (int w = 0; w < NTHR2 / 64; ++w) s += ytmp[w];
                    atomicAdd(out, s);
                }
            }
        }
    }
}

// ---------------- fallback: proven R1 gather kernel ----------------
__global__ __launch_bounds__(256) void wasll_fallback(
    const float2* __restrict__ pos, const int4* __restrict__ fnp4,
    const float* __restrict__ net_weights, const float* __restrict__ inv_gamma_p,
    const int* __restrict__ slrx_p, const int* __restrict__ slry_p,
    float* __restrict__ out, int num_nets)
{
    const float ig = inv_gamma_p[0];
    const float dx = (slrx_p[0] > 1) ? 1.0f : 0.0f;
    const float dy = (slry_p[0] > 1) ? 1.0f : 0.0f;
    int net = blockIdx.x * blockDim.x + threadIdx.x;
    float val = 0.0f;
    if (net < num_nets) {
        int4 idx = fnp4[net];
        float2 p0 = pos[idx.x], p1 = pos[idx.y], p2 = pos[idx.z], p3 = pos[idx.w];
        val = net_weights[net] * (dx * wa4(p0.x, p1.x, p2.x, p3.x, ig)
                                + dy * wa4(p0.y, p1.y, p2.y, p3.y, ig));
    }
    #pragma unroll
    for (int off = 32; off > 0; off >>= 1) val += __shfl_down(val, off, 64);
    __shared__ float smem[4];
    if ((threadIdx.x & 63) == 0) smem[threadIdx.x >> 6] = val;
    __syncthreads();
    if (threadIdx.x == 0)
        atomicAdd(out, smem[0] + smem[1] + smem[2] + smem[3]);
}

__global__ void zero_out_kernel(float* __restrict__ out) { out[0] = 0.0f; }

extern "C" void kernel_launch(void* const* d_in, const int* in_sizes, int n_in,
                              void* d_out, int out_size, void* d_ws, size_t ws_size,
                              hipStream_t stream) {
    const float* posf        = (const float*)d_in[0];
    const int*   fnp         = (const int*)d_in[1];
    const float* net_weights = (const float*)d_in[4];
    const float* inv_gamma   = (const float*)d_in[7];
    const int*   slrx        = (const int*)d_in[8];
    const int*   slry        = (const int*)d_in[9];
    float*       out         = (float*)d_out;
    const int    N  = in_sizes[4];
    const int    NP = in_sizes[1];

    const int n_pinb = (NP + PINB_SIZE - 1) >> PINB_SHIFT;
    const int n_jb   = (NP + JB_SIZE - 1) >> JB_SHIFT;

    size_t off = 0;
    auto carve = [&](size_t bytes) { size_t o = off; off += (bytes + 255) & ~size_t(255); return o; };
    size_t o_ent1  = carve((size_t)n_pinb * PINB_SIZE * sizeof(uint2));
    size_t o_ent2a = carve((size_t)n_jb * JB_SIZE * sizeof(uint2));
    size_t o_ent2b = carve((size_t)n_jb * JB_SIZE * sizeof(uint2));
    size_t o_cur1  = carve((size_t)MAX_PINB * sizeof(unsigned));
    size_t o_cur2  = carve((size_t)2 * MAX_JB * sizeof(unsigned));
    size_t o_bar   = carve(256);
    const size_t zero_span = (o_bar + 256) - o_cur1;   // cur1+cur2+bar adjacent

    const bool ok = (NP == 4 * N) && (NP % 4 == 0) && (NP > 0) &&
                    (n_pinb <= MAX_PINB) && (n_jb <= MAX_JB) && (off <= ws_size);
    if (!ok) {
        hipLaunchKernelGGL(zero_out_kernel, dim3(1), dim3(1), 0, stream, out);
        const int block = 256, grid = (N + block - 1) / block;
        hipLaunchKernelGGL(wasll_fallback, dim3(grid), dim3(block), 0, stream,
                           (const float2*)posf, (const int4*)fnp, net_weights,
                           inv_gamma, slrx, slry, out, N);
        return;
    }

    char* ws = (char*)d_ws;
    uint2*    ent1  = (uint2*)(ws + o_ent1);
    uint2*    ent2a = (uint2*)(ws + o_ent2a);
    uint2*    ent2b = (uint2*)(ws + o_ent2b);
    unsigned* cur1  = (unsigned*)(ws + o_cur1);
    unsigned* cur2  = (unsigned*)(ws + o_cur2);
    unsigned* bar   = (unsigned*)(ws + o_bar);

    // one memset for cursors + barrier counter; 2 dispatches total
    hipMemsetAsync(ws + o_cur1, 0, zero_span, stream);
    hipLaunchKernelGGL(fused_wasll, dim3(NBLK), dim3(NTHR2), 0, stream,
                       (const int4*)fnp, (const float2*)posf, net_weights,
                       inv_gamma, slrx, slry, NP, n_pinb, n_jb,
                       ent1, ent2a, ent2b, cur1, cur2, bar, out);
}